// Round 1
// 426.081 us; speedup vs baseline: 1.0512x; 1.0512x over previous
//
#include <hip/hip_runtime.h>
#include <float.h>

#define BB 16
#define NN 4096
#define CC 64
#define KNN 32
#define NSLICE 16   // select slices per query (was 8)
#define SSZ 256     // NN / NSLICE
#define CKEEP 8     // kept per slice; P(slice holds >=8 of top-32) ~ 5.5e-4
                    // => ~700-1000 flagged queries, handled by wave-parallel
                    // exact fallback (~12k cyc/query-wave, ~5-15 us total)
#define NPART 4     // emit partitions
#define PSZ 1024
#define NQ 65536

// ===========================================================================
// KNN, reference arithmetic VARIANT V2 (verified bit-compatible since R4):
//   dot = fma(z,z', fma(y,y', x*x'));  xx = ((x*x + y*y) + z*z)  [rn, no fma]
//   pd  = ((dot+dot) - qxx) - xx_c     [left-assoc rn]
//
// R10: med3 = 4.3 cyc (issue-bound). R11 (this round): chain 16 -> 8 by
// doubling slices to 16 and making the fallback cheap instead of rare:
// merge compacts flagged queries (atomicAdd list); fallback is one wave
// per flagged query doing an exact bitwise radix-select on monotonic
// float keys held in 64 statically-indexed VGPRs. Unflagged path is
// bit-identical to previous version; flagged path is exact.
// ===========================================================================

#define M3 __builtin_amdgcn_fmed3f

// 8-deep descending insert: h07=med3(pd,h07,h06) ... h00=max(h00,pd)
#define CHAIN8 \
  h07=M3(pd,h07,h06); h06=M3(pd,h06,h05); h05=M3(pd,h05,h04); \
  h04=M3(pd,h04,h03); h03=M3(pd,h03,h02); h02=M3(pd,h02,h01); \
  h01=M3(pd,h01,h00); h00=fmaxf(h00,pd);

#define H8_DECL \
  float h00=-FLT_MAX,h01=-FLT_MAX,h02=-FLT_MAX,h03=-FLT_MAX, \
        h04=-FLT_MAX,h05=-FLT_MAX,h06=-FLT_MAX,h07=-FLT_MAX;

// --------------------------------------------------------------------------
// A: select. grid 4096 = (b<<8)|(g<<4)|s, 256 thr = 256 queries. LDS 4 KB.
// --------------------------------------------------------------------------
__global__ __launch_bounds__(256) void knn_select_kernel(
        const float* __restrict__ xyz, float* __restrict__ val_buf,
        int* __restrict__ flag_cnt) {
#pragma clang fp contract(off)
    __shared__ float4 pts[SSZ];
    const int tid = threadIdx.x;
    const int blk = blockIdx.x;
    if (blk == 0 && tid == 0) flag_cnt[0] = 0;  // ordered before merge
    const int s = blk & 15;
    const int g = (blk >> 4) & 15;
    const int b = blk >> 8;
    const float* xb = xyz + (size_t)b * (3 * NN);

    for (int j = tid; j < SSZ; j += 256) {
        int i = (s << 8) | j;
        float x = xb[i], y = xb[NN + i], z = xb[2 * NN + i];
        float xx = ((x * x) + (y * y)) + (z * z);  // rn (contract off)
        pts[j] = make_float4(x, y, z, xx);
    }
    const int q = (g << 8) | tid;
    const float qx = xb[q], qy = xb[NN + q], qz = xb[2 * NN + q];
    const float qxx = ((qx * qx) + (qy * qy)) + (qz * qz);
    __syncthreads();

    H8_DECL
#pragma unroll 4
    for (int j = 0; j < SSZ; ++j) {
        float4 cp = pts[j];
        float dot = __builtin_fmaf(qz, cp.z, __builtin_fmaf(qy, cp.y, qx * cp.x));
        float pd = ((dot + dot) - qxx) - cp.w;
        CHAIN8
    }

    const int qg = (b << 12) | q;
    float* vp = val_buf + (size_t)(s * CKEEP) * NQ + qg;  // desc order t=0..7
#define ST(t, ht) vp[(size_t)(t) * NQ] = ht;
    ST(0,h00) ST(1,h01) ST(2,h02) ST(3,h03)
    ST(4,h04) ST(5,h05) ST(6,h06) ST(7,h07)
#undef ST
}

// --------------------------------------------------------------------------
// B: merge. 64-thr blocks; stage 16x8=128 values/query to LDS (stride 129);
// 16-head sequential merge -> T (32nd largest); certificate: every slice's
// 8th value < T, else append query to compacted flag list for the exact
// wave-parallel fallback. Counts per emit-partition (slice s -> s>>2).
// --------------------------------------------------------------------------
__global__ __launch_bounds__(64) void knn_merge_kernel(
        const float* __restrict__ val_buf, float* __restrict__ T_buf,
        int* __restrict__ pack_buf, int* __restrict__ flag_list,
        int* __restrict__ flag_cnt) {
    __shared__ float lv[64 * 129];  // 33 KB
    const int tid = threadIdx.x;
    const int qg = blockIdx.x * 64 + tid;
    float* my = lv + tid * 129;
    for (int t = 0; t < 128; ++t) my[t] = val_buf[(size_t)t * NQ + qg];

    int p0=0,p1=0,p2=0,p3=0,p4=0,p5=0,p6=0,p7=0,
        p8=0,p9=0,p10=0,p11=0,p12=0,p13=0,p14=0,p15=0;
    float v0 =my[0],  v1 =my[8],  v2 =my[16],  v3 =my[24];
    float v4 =my[32], v5 =my[40], v6 =my[48],  v7 =my[56];
    float v8 =my[64], v9 =my[72], v10=my[80],  v11=my[88];
    float v12=my[96], v13=my[104],v14=my[112], v15=my[120];
    float T = -FLT_MAX;
    for (int step = 0; step < 32; ++step) {
        float best = v0; int bp = 0;
        if (v1  > best) { best = v1;  bp = 1; }
        if (v2  > best) { best = v2;  bp = 2; }
        if (v3  > best) { best = v3;  bp = 3; }
        if (v4  > best) { best = v4;  bp = 4; }
        if (v5  > best) { best = v5;  bp = 5; }
        if (v6  > best) { best = v6;  bp = 6; }
        if (v7  > best) { best = v7;  bp = 7; }
        if (v8  > best) { best = v8;  bp = 8; }
        if (v9  > best) { best = v9;  bp = 9; }
        if (v10 > best) { best = v10; bp = 10; }
        if (v11 > best) { best = v11; bp = 11; }
        if (v12 > best) { best = v12; bp = 12; }
        if (v13 > best) { best = v13; bp = 13; }
        if (v14 > best) { best = v14; bp = 14; }
        if (v15 > best) { best = v15; bp = 15; }
        T = best;
        if      (bp==0)  { ++p0;  v0  = (p0 <8)?my[p0]      :-FLT_MAX; }
        else if (bp==1)  { ++p1;  v1  = (p1 <8)?my[8+p1]    :-FLT_MAX; }
        else if (bp==2)  { ++p2;  v2  = (p2 <8)?my[16+p2]   :-FLT_MAX; }
        else if (bp==3)  { ++p3;  v3  = (p3 <8)?my[24+p3]   :-FLT_MAX; }
        else if (bp==4)  { ++p4;  v4  = (p4 <8)?my[32+p4]   :-FLT_MAX; }
        else if (bp==5)  { ++p5;  v5  = (p5 <8)?my[40+p5]   :-FLT_MAX; }
        else if (bp==6)  { ++p6;  v6  = (p6 <8)?my[48+p6]   :-FLT_MAX; }
        else if (bp==7)  { ++p7;  v7  = (p7 <8)?my[56+p7]   :-FLT_MAX; }
        else if (bp==8)  { ++p8;  v8  = (p8 <8)?my[64+p8]   :-FLT_MAX; }
        else if (bp==9)  { ++p9;  v9  = (p9 <8)?my[72+p9]   :-FLT_MAX; }
        else if (bp==10) { ++p10; v10 = (p10<8)?my[80+p10]  :-FLT_MAX; }
        else if (bp==11) { ++p11; v11 = (p11<8)?my[88+p11]  :-FLT_MAX; }
        else if (bp==12) { ++p12; v12 = (p12<8)?my[96+p12]  :-FLT_MAX; }
        else if (bp==13) { ++p13; v13 = (p13<8)?my[104+p13] :-FLT_MAX; }
        else if (bp==14) { ++p14; v14 = (p14<8)?my[112+p14] :-FLT_MAX; }
        else             { ++p15; v15 = (p15<8)?my[120+p15] :-FLT_MAX; }
    }

    int gt0=0,gt1=0,gt2=0,gt3=0, eq0=0,eq1=0,eq2=0,eq3=0;
    bool flag = false;
    for (int sl = 0; sl < 16; ++sl) {
        const int base = sl * 8;
        int g_ = 0, e_ = 0;
        for (int t = 0; t < 8; ++t) {
            float v = my[base + t];
            g_ += (v > T); e_ += (v == T);
        }
        const int gp = sl >> 2;
        if      (gp == 0) { gt0 += g_; eq0 += e_; }
        else if (gp == 1) { gt1 += g_; eq1 += e_; }
        else if (gp == 2) { gt2 += g_; eq2 += e_; }
        else              { gt3 += g_; eq3 += e_; }
        flag = flag || (my[base + 7] >= T);  // certificate violation
    }

    T_buf[qg] = T;
    if (flag) {
        int pos = atomicAdd(flag_cnt, 1);
        flag_list[pos] = qg;
    }
    int budget = 32 - (gt0 + gt1 + gt2 + gt3);
    int t0 = min(eq0, budget); budget -= t0;
    int t1 = min(eq1, budget); budget -= t1;
    int t2 = min(eq2, budget); budget -= t2;
    int t3 = min(eq3, budget);
    int base = 0;
    pack_buf[qg*4+0] = base | (gt0<<8) | ((gt0+t0)<<16); base += gt0+t0;
    pack_buf[qg*4+1] = base | (gt1<<8) | ((gt1+t1)<<16); base += gt1+t1;
    pack_buf[qg*4+2] = base | (gt2<<8) | ((gt2+t2)<<16); base += gt2+t2;
    pack_buf[qg*4+3] = base | (gt3<<8) | ((gt3+t3)<<16);
}

// --------------------------------------------------------------------------
// B2: exact fallback, wave-per-query over the compacted flag list.
// 64 lanes x 64 points; pd -> monotonic uint key in 64 statically-indexed
// VGPRs; 32-step bitwise search for the exact 32nd-largest key (count via
// shfl_xor butterfly); then exact per-partition gt/eq counts + pack.
// ~12k cyc per query-wave; exact regardless of flag rate.
// --------------------------------------------------------------------------
__global__ __launch_bounds__(256) void knn_fallback_kernel(
        const float* __restrict__ xyz, const int* __restrict__ flag_list,
        const int* __restrict__ flag_cnt, float* __restrict__ T_buf,
        int* __restrict__ pack_buf) {
#pragma clang fp contract(off)
    const int nflag = flag_cnt[0];
    const int lane = threadIdx.x & 63;
    const int wid = (blockIdx.x * 256 + threadIdx.x) >> 6;
    const int nw = (gridDim.x * 256) >> 6;
    for (int w = wid; w < nflag; w += nw) {
        const int qg = flag_list[w];
        const int b = qg >> 12;
        const int q = qg & (NN - 1);
        const float* xb = xyz + (size_t)b * (3 * NN);
        const float qx = xb[q], qy = xb[NN + q], qz = xb[2 * NN + q];
        const float qxx = ((qx * qx) + (qy * qy)) + (qz * qz);

        // keys: monotonic map of pd (pd is never -0: subtrahend xx_c > 0)
        unsigned key[64];
#pragma unroll
        for (int i = 0; i < 64; ++i) {
            const int j = (i << 6) | lane;
            float x = xb[j], y = xb[NN + j], z = xb[2 * NN + j];
            float xxc = ((x * x) + (y * y)) + (z * z);
            float dot = __builtin_fmaf(qz, z, __builtin_fmaf(qy, y, qx * x));
            float pd = ((dot + dot) - qxx) - xxc;
            unsigned u = __float_as_uint(pd);
            key[i] = u ^ ((u >> 31) ? 0xFFFFFFFFu : 0x80000000u);
        }

        // largest t with #{key >= t} >= 32  ==  32nd-largest key
        unsigned cur = 0u;
        for (int bit = 31; bit >= 0; --bit) {
            const unsigned cand = cur | (1u << bit);
            int c = 0;
#pragma unroll
            for (int i = 0; i < 64; ++i) c += (key[i] >= cand) ? 1 : 0;
#pragma unroll
            for (int o = 32; o >= 1; o >>= 1) c += __shfl_xor(c, o, 64);
            if (c >= 32) cur = cand;  // c uniform after butterfly
        }
        const float T = __uint_as_float(
            (cur & 0x80000000u) ? (cur ^ 0x80000000u) : ~cur);

        // exact per-partition counts (lane's point i -> partition i>>4)
        int gtv[4], eqv[4];
#pragma unroll
        for (int p = 0; p < 4; ++p) {
            int ge = 0;
#pragma unroll
            for (int i = p * 16; i < p * 16 + 16; ++i) {
                ge += (key[i] > cur) ? 1 : 0;
                ge += (key[i] == cur) ? 0x10000 : 0;
            }
#pragma unroll
            for (int o = 32; o >= 1; o >>= 1) ge += __shfl_xor(ge, o, 64);
            gtv[p] = ge & 0xFFFF;
            eqv[p] = ge >> 16;
        }

        if (lane == 0) {
            T_buf[qg] = T;
            int budget = 32 - (gtv[0] + gtv[1] + gtv[2] + gtv[3]);
            int base = 0;
#pragma unroll
            for (int p = 0; p < 4; ++p) {
                int tp = min(eqv[p], budget); budget -= tp;
                pack_buf[qg*4+p] = base | (gtv[p]<<8) | ((gtv[p]+tp)<<16);
                base += gtv[p] + tp;
            }
        }
    }
}

// --------------------------------------------------------------------------
// C: emit: re-scan 4 partitions of 1024 with T, write indices.
// --------------------------------------------------------------------------
__global__ __launch_bounds__(256) void knn_emit_kernel(
        const float* __restrict__ xyz, const float* __restrict__ T_buf,
        const int* __restrict__ pack_buf, int* __restrict__ idx_out) {
#pragma clang fp contract(off)
    __shared__ float4 pts[PSZ];
    const int tid = threadIdx.x;
    const int blk = blockIdx.x;
    const int p = blk & 3;
    const int g = (blk >> 2) & 15;
    const int b = blk >> 6;
    const float* xb = xyz + (size_t)b * (3 * NN);

    for (int j = tid; j < PSZ; j += 256) {
        int i = (p << 10) | j;
        float x = xb[i], y = xb[NN + i], z = xb[2 * NN + i];
        float xx = ((x * x) + (y * y)) + (z * z);
        pts[j] = make_float4(x, y, z, xx);
    }
    const int q = (g << 8) | tid;
    const float qx = xb[q], qy = xb[NN + q], qz = xb[2 * NN + q];
    const float qxx = ((qx * qx) + (qy * qy)) + (qz * qz);
    __syncthreads();

    const int qg = (b << 12) | q;
    const float T = T_buf[qg];
    const int pk = pack_buf[qg * 4 + p];
    int slot = pk & 255;
    const int sp = (pk >> 8) & 255;
    const int np = (pk >> 16) & 255;
    int tie_slot = slot + sp;
    const int tie_end = slot + np;
    int* outp = idx_out + (size_t)qg * KNN;

#pragma unroll 2
    for (int j = 0; j < PSZ; ++j) {
        float4 cp = pts[j];
        float dot = __builtin_fmaf(qz, cp.z, __builtin_fmaf(qy, cp.y, qx * cp.x));
        float pd = ((dot + dot) - qxx) - cp.w;
        if (pd > T) {
            outp[slot++] = (p << 10) | j;
        } else if (pd == T && tie_slot < tie_end) {
            outp[tie_slot++] = (p << 10) | j;
        }
    }
}

// --------------------------------------------------------------------------
// gather / sigma / finalize: unchanged.
// --------------------------------------------------------------------------
__global__ __launch_bounds__(256) void gather_minmax_kernel(
        const float* __restrict__ feats, const int* __restrict__ idx_in,
        float* __restrict__ mx_buf, float* __restrict__ mn_buf,
        double* __restrict__ partials) {
    const int tid = threadIdx.x;
    const int w = tid >> 6;
    const int lane = tid & 63;
    const int q = blockIdx.x * 4 + w;
    const int b = q >> 12;
    const float* fb = feats + (size_t)b * (NN * CC);
    const float center = feats[(size_t)q * CC + lane];
    const int* ip = idx_in + (size_t)q * KNN;

    float mx = -FLT_MAX, mn = FLT_MAX;
    double ss = 0.0;
#pragma unroll 4
    for (int k = 0; k < KNN; ++k) {
        int nb = ip[k];
        float v = fb[(size_t)nb * CC + lane];
        float off = v - center;
        mx = fmaxf(mx, off);
        mn = fminf(mn, off);
        double od = (double)off;
        ss = fma(od, od, ss);
    }
    mx_buf[(size_t)q * CC + lane] = mx;
    mn_buf[(size_t)q * CC + lane] = mn;

#pragma unroll
    for (int o = 32; o >= 1; o >>= 1) ss += __shfl_down(ss, o, 64);
    __shared__ double wsum[4];
    if (lane == 0) wsum[w] = ss;
    __syncthreads();
    if (tid == 0) partials[blockIdx.x] = (wsum[0] + wsum[1]) + (wsum[2] + wsum[3]);
}

__global__ __launch_bounds__(256) void sigma_kernel(const double* __restrict__ partials,
                                                    float* __restrict__ sigma) {
    __shared__ double red[256];
    double s = 0.0;
    for (int i = threadIdx.x; i < 16384; i += 256) s += partials[i];
    red[threadIdx.x] = s;
    __syncthreads();
    for (int o = 128; o >= 1; o >>= 1) {
        if (threadIdx.x < o) red[threadIdx.x] += red[threadIdx.x + o];
        __syncthreads();
    }
    if (threadIdx.x == 0) sigma[0] = (float)(red[0] * (1.0 / 134217728.0));
}

__global__ __launch_bounds__(256) void finalize_kernel(
        const float* __restrict__ mx_buf, const float* __restrict__ mn_buf,
        const float* __restrict__ alpha, const float* __restrict__ beta,
        const float* __restrict__ sigma, float* __restrict__ out) {
#pragma clang fp contract(off)
    const int e = blockIdx.x * 256 + threadIdx.x;
    const int c = e & (CC - 1);
    const float s = sigma[0] + 1e-5f;
    const float a = alpha[c];
    const float bt = beta[c];
    const float off = (a >= 0.f) ? mx_buf[e] : mn_buf[e];
    const float t = off / s;
    out[e] = (t * a) + bt;
}

extern "C" void kernel_launch(void* const* d_in, const int* in_sizes, int n_in,
                              void* d_out, int out_size, void* d_ws, size_t ws_size,
                              hipStream_t stream) {
    (void)in_sizes; (void)n_in; (void)out_size; (void)ws_size;
    const float* xyz   = (const float*)d_in[0];  // [16,3,4096]
    const float* feats = (const float*)d_in[1];  // [16,4096,64]
    const float* alpha = (const float*)d_in[2];  // [64]
    const float* beta  = (const float*)d_in[3];  // [64]
    float* out = (float*)d_out;                  // [16,4096,64]

    char* ws = (char*)d_ws;
    // Lifetimes: val(select->merge) aliases idx/mx/mn (emit->finalize);
    // flag_list/cnt live merge->fallback, placed in mn_buf's tail beyond
    // val_buf's extent (mn written only by gather, after fallback);
    // T/pack live merge->emit; partials+sigma alias T after emit.
    float*  val_buf  = (float*)ws;                   // [0, 33,554,432)
    int*    idx_buf  = (int*)ws;                     // alias [0, 8.4MB) post-merge
    float*  mx_buf   = (float*)(ws + 8388608);       // [8.4, 25.2MB)
    float*  mn_buf   = (float*)(ws + 25165824);      // [25.2, 41.9MB)
    int*    flag_list= (int*)(ws + 33554432);        // 256 KB, merge->fallback
    int*    flag_cnt = (int*)(ws + 33816576);        // 4 B
    float*  T_buf    = (float*)(ws + 41943040);      // 256 KB
    int*    pack_buf = (int*)(ws + 42205184);        // 1 MB
    double* partials = (double*)(ws + 41943040);     // alias T_buf (dead post-emit)
    float*  sigma    = (float*)(ws + 42074112);

    knn_select_kernel<<<BB * 16 * NSLICE, 256, 0, stream>>>(xyz, val_buf, flag_cnt);
    knn_merge_kernel<<<NQ / 64, 64, 0, stream>>>(val_buf, T_buf, pack_buf,
                                                 flag_list, flag_cnt);
    knn_fallback_kernel<<<256, 256, 0, stream>>>(xyz, flag_list, flag_cnt,
                                                 T_buf, pack_buf);
    knn_emit_kernel<<<BB * 16 * NPART, 256, 0, stream>>>(xyz, T_buf, pack_buf, idx_buf);
    gather_minmax_kernel<<<NQ / 4, 256, 0, stream>>>(feats, idx_buf, mx_buf,
                                                     mn_buf, partials);
    sigma_kernel<<<1, 256, 0, stream>>>(partials, sigma);
    finalize_kernel<<<(NQ * CC) / 256, 256, 0, stream>>>(mx_buf, mn_buf, alpha,
                                                         beta, sigma, out);
}

// Round 2
// 385.312 us; speedup vs baseline: 1.1624x; 1.1058x over previous
//
#include <hip/hip_runtime.h>
#include <float.h>

#define BB 16
#define NN 4096
#define CC 64
#define KNN 32
#define NSLICE 16   // select slices per query
#define SSZ 256     // NN / NSLICE
#define CKEEP 8     // kept per slice; P(slice holds >=8 of top-32) ~ 5.5e-4
#define NQ 65536

// ===========================================================================
// KNN, reference arithmetic VARIANT V2 (verified bit-compatible since R4):
//   dot = fma(z,z', fma(y,y', x*x'));  xx = ((x*x + y*y) + z*z)  [rn, no fma]
//   pd  = ((dot+dot) - qxx) - xx_c     [left-assoc rn]
//
// R11: chain 16->8 via 16 slices + wave-parallel exact fallback (426 us).
// R12 (this round): emit was 143 us at 57% VALUBusy -- per-thread serial
// scan with 2 divergent branches/point (~84 cyc/pt vs ~20 ideal) + 6x
// write amplification (48.9 MB WRITE_SIZE vs 8.4 MB ideal). Rewritten as
// wave-per-query ballot compaction: lane l scans points j*64+l (index
// order preserved across iterations), hits placed via ballot+mbcnt rank,
// 16 KB LDS chunks shared by 8 queries/block. pack_buf collapses to
// gt_total|(budget<<16); output slot ORDER is irrelevant (gather is
// max/mean over the set) -- only the set matches reference (ties = first
// `budget` eq-hits in index order, preserved by scan order).
// prep_kernel materializes (x,y,z,xx) float4 once; select/emit read it
// (identical formula => bit-identical).
// ===========================================================================

#define M3 __builtin_amdgcn_fmed3f

__device__ __forceinline__ int lane_rank(unsigned long long m) {
    // popcount(m & lanes_below_me)
    return __builtin_amdgcn_mbcnt_hi((unsigned)(m >> 32),
           __builtin_amdgcn_mbcnt_lo((unsigned)m, 0u));
}

// 8-deep descending insert: h07=med3(pd,h07,h06) ... h00=max(h00,pd)
#define CHAIN8 \
  h07=M3(pd,h07,h06); h06=M3(pd,h06,h05); h05=M3(pd,h05,h04); \
  h04=M3(pd,h04,h03); h03=M3(pd,h03,h02); h02=M3(pd,h02,h01); \
  h01=M3(pd,h01,h00); h00=fmaxf(h00,pd);

#define H8_DECL \
  float h00=-FLT_MAX,h01=-FLT_MAX,h02=-FLT_MAX,h03=-FLT_MAX, \
        h04=-FLT_MAX,h05=-FLT_MAX,h06=-FLT_MAX,h07=-FLT_MAX;

// --------------------------------------------------------------------------
// P: prep. pts4[b*4096+i] = (x,y,z,xx) with the V2 rn formula. Also resets
// flag_cnt (stream-ordered before merge).
// --------------------------------------------------------------------------
__global__ __launch_bounds__(256) void prep_kernel(
        const float* __restrict__ xyz, float4* __restrict__ pts4,
        int* __restrict__ flag_cnt) {
#pragma clang fp contract(off)
    const int p = blockIdx.x * 256 + threadIdx.x;
    if (p == 0) flag_cnt[0] = 0;
    const int b = p >> 12;
    const int i = p & (NN - 1);
    const float* xb = xyz + (size_t)b * (3 * NN);
    float x = xb[i], y = xb[NN + i], z = xb[2 * NN + i];
    float xx = ((x * x) + (y * y)) + (z * z);  // rn (contract off)
    pts4[p] = make_float4(x, y, z, xx);
}

// --------------------------------------------------------------------------
// A: select. grid 4096 = (b<<8)|(g<<4)|s, 256 thr = 256 queries. LDS 4 KB.
// --------------------------------------------------------------------------
__global__ __launch_bounds__(256) void knn_select_kernel(
        const float4* __restrict__ pts4, float* __restrict__ val_buf) {
#pragma clang fp contract(off)
    __shared__ float4 pts[SSZ];
    const int tid = threadIdx.x;
    const int blk = blockIdx.x;
    const int s = blk & 15;
    const int g = (blk >> 4) & 15;
    const int b = blk >> 8;
    const float4* pb = pts4 + (b << 12);

    pts[tid] = pb[(s << 8) | tid];  // SSZ == blockDim
    const int q = (g << 8) | tid;
    const float4 qp = pb[q];
    const float qx = qp.x, qy = qp.y, qz = qp.z, qxx = qp.w;
    __syncthreads();

    H8_DECL
#pragma unroll 4
    for (int j = 0; j < SSZ; ++j) {
        float4 cp = pts[j];
        float dot = __builtin_fmaf(qz, cp.z, __builtin_fmaf(qy, cp.y, qx * cp.x));
        float pd = ((dot + dot) - qxx) - cp.w;
        CHAIN8
    }

    const int qg = (b << 12) | q;
    float* vp = val_buf + (size_t)(s * CKEEP) * NQ + qg;  // desc order t=0..7
#define ST(t, ht) vp[(size_t)(t) * NQ] = ht;
    ST(0,h00) ST(1,h01) ST(2,h02) ST(3,h03)
    ST(4,h04) ST(5,h05) ST(6,h06) ST(7,h07)
#undef ST
}

// --------------------------------------------------------------------------
// B: merge. 64-thr blocks; stage 16x8=128 values/query to LDS (stride 129);
// 16-head sequential merge -> T (32nd largest); certificate: every slice's
// 8th value < T, else append query to compacted flag list. pack_buf[qg] =
// gt_total | (budget<<16).
// --------------------------------------------------------------------------
__global__ __launch_bounds__(64) void knn_merge_kernel(
        const float* __restrict__ val_buf, float* __restrict__ T_buf,
        int* __restrict__ pack_buf, int* __restrict__ flag_list,
        int* __restrict__ flag_cnt) {
    __shared__ float lv[64 * 129];  // 33 KB
    const int tid = threadIdx.x;
    const int qg = blockIdx.x * 64 + tid;
    float* my = lv + tid * 129;
    for (int t = 0; t < 128; ++t) my[t] = val_buf[(size_t)t * NQ + qg];

    int p0=0,p1=0,p2=0,p3=0,p4=0,p5=0,p6=0,p7=0,
        p8=0,p9=0,p10=0,p11=0,p12=0,p13=0,p14=0,p15=0;
    float v0 =my[0],  v1 =my[8],  v2 =my[16],  v3 =my[24];
    float v4 =my[32], v5 =my[40], v6 =my[48],  v7 =my[56];
    float v8 =my[64], v9 =my[72], v10=my[80],  v11=my[88];
    float v12=my[96], v13=my[104],v14=my[112], v15=my[120];
    float T = -FLT_MAX;
    for (int step = 0; step < 32; ++step) {
        float best = v0; int bp = 0;
        if (v1  > best) { best = v1;  bp = 1; }
        if (v2  > best) { best = v2;  bp = 2; }
        if (v3  > best) { best = v3;  bp = 3; }
        if (v4  > best) { best = v4;  bp = 4; }
        if (v5  > best) { best = v5;  bp = 5; }
        if (v6  > best) { best = v6;  bp = 6; }
        if (v7  > best) { best = v7;  bp = 7; }
        if (v8  > best) { best = v8;  bp = 8; }
        if (v9  > best) { best = v9;  bp = 9; }
        if (v10 > best) { best = v10; bp = 10; }
        if (v11 > best) { best = v11; bp = 11; }
        if (v12 > best) { best = v12; bp = 12; }
        if (v13 > best) { best = v13; bp = 13; }
        if (v14 > best) { best = v14; bp = 14; }
        if (v15 > best) { best = v15; bp = 15; }
        T = best;
        if      (bp==0)  { ++p0;  v0  = (p0 <8)?my[p0]      :-FLT_MAX; }
        else if (bp==1)  { ++p1;  v1  = (p1 <8)?my[8+p1]    :-FLT_MAX; }
        else if (bp==2)  { ++p2;  v2  = (p2 <8)?my[16+p2]   :-FLT_MAX; }
        else if (bp==3)  { ++p3;  v3  = (p3 <8)?my[24+p3]   :-FLT_MAX; }
        else if (bp==4)  { ++p4;  v4  = (p4 <8)?my[32+p4]   :-FLT_MAX; }
        else if (bp==5)  { ++p5;  v5  = (p5 <8)?my[40+p5]   :-FLT_MAX; }
        else if (bp==6)  { ++p6;  v6  = (p6 <8)?my[48+p6]   :-FLT_MAX; }
        else if (bp==7)  { ++p7;  v7  = (p7 <8)?my[56+p7]   :-FLT_MAX; }
        else if (bp==8)  { ++p8;  v8  = (p8 <8)?my[64+p8]   :-FLT_MAX; }
        else if (bp==9)  { ++p9;  v9  = (p9 <8)?my[72+p9]   :-FLT_MAX; }
        else if (bp==10) { ++p10; v10 = (p10<8)?my[80+p10]  :-FLT_MAX; }
        else if (bp==11) { ++p11; v11 = (p11<8)?my[88+p11]  :-FLT_MAX; }
        else if (bp==12) { ++p12; v12 = (p12<8)?my[96+p12]  :-FLT_MAX; }
        else if (bp==13) { ++p13; v13 = (p13<8)?my[104+p13] :-FLT_MAX; }
        else if (bp==14) { ++p14; v14 = (p14<8)?my[112+p14] :-FLT_MAX; }
        else             { ++p15; v15 = (p15<8)?my[120+p15] :-FLT_MAX; }
    }

    int gt = 0, eq = 0;
    bool flag = false;
    for (int sl = 0; sl < 16; ++sl) {
        const int base = sl * 8;
        for (int t = 0; t < 8; ++t) {
            float v = my[base + t];
            gt += (v > T); eq += (v == T);
        }
        flag = flag || (my[base + 7] >= T);  // certificate violation
    }

    T_buf[qg] = T;
    if (flag) {
        int pos = atomicAdd(flag_cnt, 1);
        flag_list[pos] = qg;
    }
    const int budget = min(eq, 32 - gt);
    pack_buf[qg] = gt | (budget << 16);
}

// --------------------------------------------------------------------------
// B2: exact fallback, wave-per-query over the compacted flag list.
// 64 lanes x 64 points; bitwise radix-select on monotonic keys in VGPRs.
// --------------------------------------------------------------------------
__global__ __launch_bounds__(256) void knn_fallback_kernel(
        const float* __restrict__ xyz, const int* __restrict__ flag_list,
        const int* __restrict__ flag_cnt, float* __restrict__ T_buf,
        int* __restrict__ pack_buf) {
#pragma clang fp contract(off)
    const int nflag = flag_cnt[0];
    const int lane = threadIdx.x & 63;
    const int wid = (blockIdx.x * 256 + threadIdx.x) >> 6;
    const int nw = (gridDim.x * 256) >> 6;
    for (int w = wid; w < nflag; w += nw) {
        const int qg = flag_list[w];
        const int b = qg >> 12;
        const int q = qg & (NN - 1);
        const float* xb = xyz + (size_t)b * (3 * NN);
        const float qx = xb[q], qy = xb[NN + q], qz = xb[2 * NN + q];
        const float qxx = ((qx * qx) + (qy * qy)) + (qz * qz);

        // keys: monotonic map of pd
        unsigned key[64];
#pragma unroll
        for (int i = 0; i < 64; ++i) {
            const int j = (i << 6) | lane;
            float x = xb[j], y = xb[NN + j], z = xb[2 * NN + j];
            float xxc = ((x * x) + (y * y)) + (z * z);
            float dot = __builtin_fmaf(qz, z, __builtin_fmaf(qy, y, qx * x));
            float pd = ((dot + dot) - qxx) - xxc;
            unsigned u = __float_as_uint(pd);
            key[i] = u ^ ((u >> 31) ? 0xFFFFFFFFu : 0x80000000u);
        }

        // largest t with #{key >= t} >= 32  ==  32nd-largest key
        unsigned cur = 0u;
        for (int bit = 31; bit >= 0; --bit) {
            const unsigned cand = cur | (1u << bit);
            int c = 0;
#pragma unroll
            for (int i = 0; i < 64; ++i) c += (key[i] >= cand) ? 1 : 0;
#pragma unroll
            for (int o = 32; o >= 1; o >>= 1) c += __shfl_xor(c, o, 64);
            if (c >= 32) cur = cand;  // c uniform after butterfly
        }
        const float T = __uint_as_float(
            (cur & 0x80000000u) ? (cur ^ 0x80000000u) : ~cur);

        // exact global gt/eq counts
        int ge = 0;
#pragma unroll
        for (int i = 0; i < 64; ++i) {
            ge += (key[i] > cur) ? 1 : 0;
            ge += (key[i] == cur) ? 0x10000 : 0;
        }
#pragma unroll
        for (int o = 32; o >= 1; o >>= 1) ge += __shfl_xor(ge, o, 64);
        const int gt_total = ge & 0xFFFF;
        const int eq_total = ge >> 16;

        if (lane == 0) {
            T_buf[qg] = T;
            const int budget = min(eq_total, 32 - gt_total);
            pack_buf[qg] = gt_total | (budget << 16);
        }
    }
}

// --------------------------------------------------------------------------
// C: emit. Wave-per-query ballot compaction. Block = 512 thr = 8 queries;
// 4 chunks of 1024 pts staged to 16 KB LDS; lane l scans points j*64+l
// (index order preserved: iteration-major, lane-minor). gt hits -> slots
// [0, gt_total); first `budget` eq hits -> [gt_total, 32). Slot order is
// irrelevant downstream (max/mean over set).
// --------------------------------------------------------------------------
__global__ __launch_bounds__(512) void knn_emit_kernel(
        const float4* __restrict__ pts4, const float* __restrict__ T_buf,
        const int* __restrict__ pack_buf, int* __restrict__ idx_out) {
#pragma clang fp contract(off)
    __shared__ float4 chunk[1024];  // 16 KB
    const int tid = threadIdx.x;
    const int lane = tid & 63;
    const int qg = (blockIdx.x << 3) | (tid >> 6);
    const int b = qg >> 12;
    const float4* pb = pts4 + (b << 12);
    const float4 qp = pb[qg & (NN - 1)];
    const float qx = qp.x, qy = qp.y, qz = qp.z, qxx = qp.w;
    const float T = T_buf[qg];
    const int pk = pack_buf[qg];
    const int g_total = pk & 0xFFFF;
    const int budget = pk >> 16;
    int* outp = idx_out + (size_t)qg * KNN;
    int slot = 0, neq = 0;

    for (int c = 0; c < 4; ++c) {
        __syncthreads();  // protect chunk reuse (harmless first iter)
        chunk[tid] = pb[(c << 10) | tid];
        chunk[tid + 512] = pb[(c << 10) | (tid + 512)];
        __syncthreads();
#pragma unroll 4
        for (int j = 0; j < 16; ++j) {
            const int il = (j << 6) | lane;
            float4 cp = chunk[il];
            float dot = __builtin_fmaf(qz, cp.z, __builtin_fmaf(qy, cp.y, qx * cp.x));
            float pd = ((dot + dot) - qxx) - cp.w;
            const bool gt = pd > T;
            const bool eq = pd == T;
            const unsigned long long mgt = __ballot(gt);
            const unsigned long long meq = __ballot(eq);
            if (gt) outp[slot + lane_rank(mgt)] = (c << 10) | il;
            if (eq) {
                const int r = neq + lane_rank(meq);
                if (r < budget) outp[g_total + r] = (c << 10) | il;
            }
            slot += __builtin_popcountll(mgt);
            neq += __builtin_popcountll(meq);
        }
    }
}

// --------------------------------------------------------------------------
// gather / sigma / finalize: unchanged.
// --------------------------------------------------------------------------
__global__ __launch_bounds__(256) void gather_minmax_kernel(
        const float* __restrict__ feats, const int* __restrict__ idx_in,
        float* __restrict__ mx_buf, float* __restrict__ mn_buf,
        double* __restrict__ partials) {
    const int tid = threadIdx.x;
    const int w = tid >> 6;
    const int lane = tid & 63;
    const int q = blockIdx.x * 4 + w;
    const int b = q >> 12;
    const float* fb = feats + (size_t)b * (NN * CC);
    const float center = feats[(size_t)q * CC + lane];
    const int* ip = idx_in + (size_t)q * KNN;

    float mx = -FLT_MAX, mn = FLT_MAX;
    double ss = 0.0;
#pragma unroll 4
    for (int k = 0; k < KNN; ++k) {
        int nb = ip[k];
        float v = fb[(size_t)nb * CC + lane];
        float off = v - center;
        mx = fmaxf(mx, off);
        mn = fminf(mn, off);
        double od = (double)off;
        ss = fma(od, od, ss);
    }
    mx_buf[(size_t)q * CC + lane] = mx;
    mn_buf[(size_t)q * CC + lane] = mn;

#pragma unroll
    for (int o = 32; o >= 1; o >>= 1) ss += __shfl_down(ss, o, 64);
    __shared__ double wsum[4];
    if (lane == 0) wsum[w] = ss;
    __syncthreads();
    if (tid == 0) partials[blockIdx.x] = (wsum[0] + wsum[1]) + (wsum[2] + wsum[3]);
}

__global__ __launch_bounds__(256) void sigma_kernel(const double* __restrict__ partials,
                                                    float* __restrict__ sigma) {
    __shared__ double red[256];
    double s = 0.0;
    for (int i = threadIdx.x; i < 16384; i += 256) s += partials[i];
    red[threadIdx.x] = s;
    __syncthreads();
    for (int o = 128; o >= 1; o >>= 1) {
        if (threadIdx.x < o) red[threadIdx.x] += red[threadIdx.x + o];
        __syncthreads();
    }
    if (threadIdx.x == 0) sigma[0] = (float)(red[0] * (1.0 / 134217728.0));
}

__global__ __launch_bounds__(256) void finalize_kernel(
        const float* __restrict__ mx_buf, const float* __restrict__ mn_buf,
        const float* __restrict__ alpha, const float* __restrict__ beta,
        const float* __restrict__ sigma, float* __restrict__ out) {
#pragma clang fp contract(off)
    const int e = blockIdx.x * 256 + threadIdx.x;
    const int c = e & (CC - 1);
    const float s = sigma[0] + 1e-5f;
    const float a = alpha[c];
    const float bt = beta[c];
    const float off = (a >= 0.f) ? mx_buf[e] : mn_buf[e];
    const float t = off / s;
    out[e] = (t * a) + bt;
}

extern "C" void kernel_launch(void* const* d_in, const int* in_sizes, int n_in,
                              void* d_out, int out_size, void* d_ws, size_t ws_size,
                              hipStream_t stream) {
    (void)in_sizes; (void)n_in; (void)out_size; (void)ws_size;
    const float* xyz   = (const float*)d_in[0];  // [16,3,4096]
    const float* feats = (const float*)d_in[1];  // [16,4096,64]
    const float* alpha = (const float*)d_in[2];  // [64]
    const float* beta  = (const float*)d_in[3];  // [64]
    float* out = (float*)d_out;                  // [16,4096,64]

    char* ws = (char*)d_ws;
    // Lifetimes: val(select->merge) aliases idx/mx/mn (emit->finalize);
    // flag_list/cnt live merge->fallback; pts4 lives prep->emit (dead
    // before gather writes mn); T/pack live merge->emit; partials+sigma
    // alias T after emit.
    float*  val_buf  = (float*)ws;                   // [0, 33,554,432)
    int*    idx_buf  = (int*)ws;                     // alias [0, 8.4MB) post-merge
    float*  mx_buf   = (float*)(ws + 8388608);       // [8.4, 25.2MB)
    float*  mn_buf   = (float*)(ws + 25165824);      // [25.2, 41.9MB)
    int*    flag_list= (int*)(ws + 33554432);        // 256 KB, merge->fallback
    int*    flag_cnt = (int*)(ws + 33816576);        // 4 B
    float4* pts4     = (float4*)(ws + 34078720);     // 1 MB, prep->emit
    float*  T_buf    = (float*)(ws + 41943040);      // 256 KB
    int*    pack_buf = (int*)(ws + 42205184);        // 256 KB
    double* partials = (double*)(ws + 41943040);     // alias T_buf (dead post-emit)
    float*  sigma    = (float*)(ws + 42074112);

    prep_kernel<<<NQ / 256, 256, 0, stream>>>(xyz, pts4, flag_cnt);
    knn_select_kernel<<<BB * 16 * NSLICE, 256, 0, stream>>>(pts4, val_buf);
    knn_merge_kernel<<<NQ / 64, 64, 0, stream>>>(val_buf, T_buf, pack_buf,
                                                 flag_list, flag_cnt);
    knn_fallback_kernel<<<256, 256, 0, stream>>>(xyz, flag_list, flag_cnt,
                                                 T_buf, pack_buf);
    knn_emit_kernel<<<NQ / 8, 512, 0, stream>>>(pts4, T_buf, pack_buf, idx_buf);
    gather_minmax_kernel<<<NQ / 4, 256, 0, stream>>>(feats, idx_buf, mx_buf,
                                                     mn_buf, partials);
    sigma_kernel<<<1, 256, 0, stream>>>(partials, sigma);
    finalize_kernel<<<(NQ * CC) / 256, 256, 0, stream>>>(mx_buf, mn_buf, alpha,
                                                         beta, sigma, out);
}

// Round 3
// 348.880 us; speedup vs baseline: 1.2838x; 1.1044x over previous
//
#include <hip/hip_runtime.h>
#include <float.h>

#define BB 16
#define NN 4096
#define CC 64
#define KNN 32
#define NSLICE 16   // select slices per query
#define SSZ 256     // NN / NSLICE
#define CKEEP 8     // kept per slice
#define NQ 65536

// ===========================================================================
// KNN via packed-key select (R13). Reference arithmetic VARIANT V2:
//   dot = fma(z,z', fma(y,y', x*x'));  xx = ((x*x + y*y) + z*z)  [rn, no fma]
//   pd  = fma(2, dot, -qxx) - xx_c    [== ((dot+dot)-qxx)-xx_c bitwise,
//                                      since 2*dot is exact]
//
// R12: ballot emit hit its issue floor (~100 us) -- the second full scan
// exists only because the med3 value-chain drops indices. R13: chain runs
// on packed u32 keys: key = (mono(pd) & 0xFFFFF000) | (4095 - idx).
// mono = u ^ (ashr(u,31)|0x80000000) is order-isomorphic to pd; keys are
// globally unique (idx in low bits). Merge's 32 picks ARE the output
// indices -- emit kernel deleted. Exactness certificate: if
// k20(key32) > k20(key33) strictly AND no slice's 8th kept >= key33, the
// packed top-32 set == exact top-32 set (strict 20-bit separation at the
// boundary implies strict pd separation; slice cert implies merge saw the
// true top-33). Either violation -> compacted flag list -> exact
// wave-per-query radix fallback (writes indices via ballot compaction,
// exact tie-by-lowest-index semantics). Correct at any flag rate.
// ===========================================================================

__device__ __forceinline__ int lane_rank(unsigned long long m) {
    return __builtin_amdgcn_mbcnt_hi((unsigned)(m >> 32),
           __builtin_amdgcn_mbcnt_lo((unsigned)m, 0u));
}

__device__ __forceinline__ unsigned med3u(unsigned a, unsigned b, unsigned c) {
    unsigned d;
    asm("v_med3_u32 %0, %1, %2, %3" : "=v"(d) : "v"(a), "v"(b), "v"(c));
    return d;
}

// 8-deep descending insert on u32 keys (h00 >= h01 >= ... >= h07)
#define UCHAIN8 \
  h07=med3u(ky,h07,h06); h06=med3u(ky,h06,h05); h05=med3u(ky,h05,h04); \
  h04=med3u(ky,h04,h03); h03=med3u(ky,h03,h02); h02=med3u(ky,h02,h01); \
  h01=med3u(ky,h01,h00); h00=(h00>ky)?h00:ky;

// --------------------------------------------------------------------------
// P: prep. pts4[b*4096+i] = (x,y,z,xx), V2 rn formula; resets flag_cnt.
// --------------------------------------------------------------------------
__global__ __launch_bounds__(256) void prep_kernel(
        const float* __restrict__ xyz, float4* __restrict__ pts4,
        int* __restrict__ flag_cnt) {
#pragma clang fp contract(off)
    const int p = blockIdx.x * 256 + threadIdx.x;
    if (p == 0) flag_cnt[0] = 0;
    const int b = p >> 12;
    const int i = p & (NN - 1);
    const float* xb = xyz + (size_t)b * (3 * NN);
    float x = xb[i], y = xb[NN + i], z = xb[2 * NN + i];
    float xx = ((x * x) + (y * y)) + (z * z);  // rn (contract off)
    pts4[p] = make_float4(x, y, z, xx);
}

// --------------------------------------------------------------------------
// A: select. grid 4096 = (b<<8)|(g<<4)|s, 256 thr = 256 queries. LDS 4 KB.
// Keeps per-slice top-8 PACKED keys (desc), stored t=0..7.
// --------------------------------------------------------------------------
__global__ __launch_bounds__(256) void knn_select_kernel(
        const float4* __restrict__ pts4, unsigned* __restrict__ val_buf) {
#pragma clang fp contract(off)
    __shared__ float4 pts[SSZ];
    const int tid = threadIdx.x;
    const int blk = blockIdx.x;
    const int s = blk & 15;
    const int g = (blk >> 4) & 15;
    const int b = blk >> 8;
    const float4* pb = pts4 + (b << 12);

    pts[tid] = pb[(s << 8) | tid];  // SSZ == blockDim
    const int q = (g << 8) | tid;
    const float4 qp = pb[q];
    const float qx = qp.x, qy = qp.y, qz = qp.z;
    const float nqxx = -qp.w;
    __syncthreads();

    unsigned h00=0,h01=0,h02=0,h03=0,h04=0,h05=0,h06=0,h07=0;
    const unsigned ibase = 4095u - (unsigned)(s << 8);  // idxterm = ibase - j
#pragma unroll 4
    for (int j = 0; j < SSZ; ++j) {
        float4 cp = pts[j];
        float dot = __builtin_fmaf(qz, cp.z, __builtin_fmaf(qy, cp.y, qx * cp.x));
        float pd = __builtin_fmaf(2.0f, dot, nqxx) - cp.w;
        unsigned u = __float_as_uint(pd);
        unsigned mono = u ^ (unsigned)(((int)u >> 31) | 0x80000000);
        unsigned ky = (mono & 0xFFFFF000u) | (ibase - (unsigned)j);
        UCHAIN8
    }

    const int qg = (b << 12) | q;
    unsigned* vp = val_buf + (size_t)(s * CKEEP) * NQ + qg;  // desc t=0..7
#define ST(t, ht) vp[(size_t)(t) * NQ] = ht;
    ST(0,h00) ST(1,h01) ST(2,h02) ST(3,h03)
    ST(4,h04) ST(5,h05) ST(6,h06) ST(7,h07)
#undef ST
}

// --------------------------------------------------------------------------
// B: merge. 64-thr blocks; stage 16x8=128 keys/query to LDS (stride 129);
// 33-step 16-head merge. First 32 picks -> idx_out directly
// (idx = 4095 - (key & 4095)). Certificates -> flag list.
// --------------------------------------------------------------------------
__global__ __launch_bounds__(64) void knn_merge_kernel(
        const unsigned* __restrict__ val_buf, int* __restrict__ idx_out,
        int* __restrict__ flag_list, int* __restrict__ flag_cnt) {
    __shared__ unsigned lv[64 * 129];  // 33 KB
    const int tid = threadIdx.x;
    const int qg = blockIdx.x * 64 + tid;
    unsigned* my = lv + tid * 129;
    for (int t = 0; t < 128; ++t) my[t] = val_buf[(size_t)t * NQ + qg];

    int p0=0,p1=0,p2=0,p3=0,p4=0,p5=0,p6=0,p7=0,
        p8=0,p9=0,p10=0,p11=0,p12=0,p13=0,p14=0,p15=0;
    unsigned v0 =my[0],  v1 =my[8],  v2 =my[16],  v3 =my[24];
    unsigned v4 =my[32], v5 =my[40], v6 =my[48],  v7 =my[56];
    unsigned v8 =my[64], v9 =my[72], v10=my[80],  v11=my[88];
    unsigned v12=my[96], v13=my[104],v14=my[112], v15=my[120];
    int* outp = idx_out + (size_t)qg * KNN;
    unsigned key32 = 0u, key33 = 0u;
    for (int step = 0; step < 33; ++step) {
        unsigned best = v0; int bp = 0;
        if (v1  > best) { best = v1;  bp = 1; }
        if (v2  > best) { best = v2;  bp = 2; }
        if (v3  > best) { best = v3;  bp = 3; }
        if (v4  > best) { best = v4;  bp = 4; }
        if (v5  > best) { best = v5;  bp = 5; }
        if (v6  > best) { best = v6;  bp = 6; }
        if (v7  > best) { best = v7;  bp = 7; }
        if (v8  > best) { best = v8;  bp = 8; }
        if (v9  > best) { best = v9;  bp = 9; }
        if (v10 > best) { best = v10; bp = 10; }
        if (v11 > best) { best = v11; bp = 11; }
        if (v12 > best) { best = v12; bp = 12; }
        if (v13 > best) { best = v13; bp = 13; }
        if (v14 > best) { best = v14; bp = 14; }
        if (v15 > best) { best = v15; bp = 15; }
        if (step == 32) { key33 = best; break; }
        outp[step] = 4095 - (int)(best & 4095u);
        if (step == 31) key32 = best;
        if      (bp==0)  { ++p0;  v0  = (p0 <8)?my[p0]      :0u; }
        else if (bp==1)  { ++p1;  v1  = (p1 <8)?my[8+p1]    :0u; }
        else if (bp==2)  { ++p2;  v2  = (p2 <8)?my[16+p2]   :0u; }
        else if (bp==3)  { ++p3;  v3  = (p3 <8)?my[24+p3]   :0u; }
        else if (bp==4)  { ++p4;  v4  = (p4 <8)?my[32+p4]   :0u; }
        else if (bp==5)  { ++p5;  v5  = (p5 <8)?my[40+p5]   :0u; }
        else if (bp==6)  { ++p6;  v6  = (p6 <8)?my[48+p6]   :0u; }
        else if (bp==7)  { ++p7;  v7  = (p7 <8)?my[56+p7]   :0u; }
        else if (bp==8)  { ++p8;  v8  = (p8 <8)?my[64+p8]   :0u; }
        else if (bp==9)  { ++p9;  v9  = (p9 <8)?my[72+p9]   :0u; }
        else if (bp==10) { ++p10; v10 = (p10<8)?my[80+p10]  :0u; }
        else if (bp==11) { ++p11; v11 = (p11<8)?my[88+p11]  :0u; }
        else if (bp==12) { ++p12; v12 = (p12<8)?my[96+p12]  :0u; }
        else if (bp==13) { ++p13; v13 = (p13<8)?my[104+p13] :0u; }
        else if (bp==14) { ++p14; v14 = (p14<8)?my[112+p14] :0u; }
        else             { ++p15; v15 = (p15<8)?my[120+p15] :0u; }
    }

    // certificates: (a) strict 20-bit separation at the 32/33 boundary;
    // (b) every slice's 8th kept key < key33 (merge saw the true top-33).
    bool flag = ((key32 >> 12) == (key33 >> 12));
    for (int sl = 0; sl < 16; ++sl)
        flag = flag || (my[sl * 8 + 7] >= key33);
    if (flag) {
        int pos = atomicAdd(flag_cnt, 1);
        flag_list[pos] = qg;
    }
}

// --------------------------------------------------------------------------
// B2: exact fallback, wave-per-query over the compacted flag list.
// Full-precision mono keys in 64 statically-indexed VGPRs; 32-step radix
// select -> exact 32nd key; indices written via ballot compaction
// (iteration-major order == index order; eq-ties take first `budget` by
// index -- exact reference tie semantics).
// --------------------------------------------------------------------------
__global__ __launch_bounds__(256) void knn_fallback_kernel(
        const float* __restrict__ xyz, const int* __restrict__ flag_list,
        const int* __restrict__ flag_cnt, int* __restrict__ idx_out) {
#pragma clang fp contract(off)
    const int nflag = flag_cnt[0];
    const int lane = threadIdx.x & 63;
    const int wid = (blockIdx.x * 256 + threadIdx.x) >> 6;
    const int nw = (gridDim.x * 256) >> 6;
    for (int w = wid; w < nflag; w += nw) {
        const int qg = flag_list[w];
        const int b = qg >> 12;
        const int q = qg & (NN - 1);
        const float* xb = xyz + (size_t)b * (3 * NN);
        const float qx = xb[q], qy = xb[NN + q], qz = xb[2 * NN + q];
        const float qxx = ((qx * qx) + (qy * qy)) + (qz * qz);
        const float nqxx = -qxx;

        unsigned key[64];
#pragma unroll
        for (int i = 0; i < 64; ++i) {
            const int j = (i << 6) | lane;
            float x = xb[j], y = xb[NN + j], z = xb[2 * NN + j];
            float xxc = ((x * x) + (y * y)) + (z * z);
            float dot = __builtin_fmaf(qz, z, __builtin_fmaf(qy, y, qx * x));
            float pd = __builtin_fmaf(2.0f, dot, nqxx) - xxc;
            unsigned u = __float_as_uint(pd);
            key[i] = u ^ (unsigned)(((int)u >> 31) | 0x80000000);
        }

        // largest t with #{key >= t} >= 32  ==  32nd-largest key
        unsigned cur = 0u;
        for (int bit = 31; bit >= 0; --bit) {
            const unsigned cand = cur | (1u << bit);
            int c = 0;
#pragma unroll
            for (int i = 0; i < 64; ++i) c += (key[i] >= cand) ? 1 : 0;
#pragma unroll
            for (int o = 32; o >= 1; o >>= 1) c += __shfl_xor(c, o, 64);
            if (c >= 32) cur = cand;  // uniform after butterfly
        }

        // exact gt/eq totals
        int ge = 0;
#pragma unroll
        for (int i = 0; i < 64; ++i) {
            ge += (key[i] > cur) ? 1 : 0;
            ge += (key[i] == cur) ? 0x10000 : 0;
        }
#pragma unroll
        for (int o = 32; o >= 1; o >>= 1) ge += __shfl_xor(ge, o, 64);
        const int gt_total = ge & 0xFFFF;
        const int budget = min(ge >> 16, 32 - gt_total);

        int* outp = idx_out + (size_t)qg * KNN;
        int slot = 0, neq = 0;
#pragma unroll
        for (int i = 0; i < 64; ++i) {
            const bool isgt = key[i] > cur;
            const bool iseq = key[i] == cur;
            const unsigned long long mgt = __ballot(isgt);
            const unsigned long long meq = __ballot(iseq);
            if (isgt) outp[slot + lane_rank(mgt)] = (i << 6) | lane;
            if (iseq) {
                const int r = neq + lane_rank(meq);
                if (r < budget) outp[gt_total + r] = (i << 6) | lane;
            }
            slot += __builtin_popcountll(mgt);
            neq += __builtin_popcountll(meq);
        }
    }
}

// --------------------------------------------------------------------------
// gather / sigma / finalize: unchanged.
// --------------------------------------------------------------------------
__global__ __launch_bounds__(256) void gather_minmax_kernel(
        const float* __restrict__ feats, const int* __restrict__ idx_in,
        float* __restrict__ mx_buf, float* __restrict__ mn_buf,
        double* __restrict__ partials) {
    const int tid = threadIdx.x;
    const int w = tid >> 6;
    const int lane = tid & 63;
    const int q = blockIdx.x * 4 + w;
    const int b = q >> 12;
    const float* fb = feats + (size_t)b * (NN * CC);
    const float center = feats[(size_t)q * CC + lane];
    const int* ip = idx_in + (size_t)q * KNN;

    float mx = -FLT_MAX, mn = FLT_MAX;
    double ss = 0.0;
#pragma unroll 4
    for (int k = 0; k < KNN; ++k) {
        int nb = ip[k];
        float v = fb[(size_t)nb * CC + lane];
        float off = v - center;
        mx = fmaxf(mx, off);
        mn = fminf(mn, off);
        double od = (double)off;
        ss = fma(od, od, ss);
    }
    mx_buf[(size_t)q * CC + lane] = mx;
    mn_buf[(size_t)q * CC + lane] = mn;

#pragma unroll
    for (int o = 32; o >= 1; o >>= 1) ss += __shfl_down(ss, o, 64);
    __shared__ double wsum[4];
    if (lane == 0) wsum[w] = ss;
    __syncthreads();
    if (tid == 0) partials[blockIdx.x] = (wsum[0] + wsum[1]) + (wsum[2] + wsum[3]);
}

__global__ __launch_bounds__(256) void sigma_kernel(const double* __restrict__ partials,
                                                    float* __restrict__ sigma) {
    __shared__ double red[256];
    double s = 0.0;
    for (int i = threadIdx.x; i < 16384; i += 256) s += partials[i];
    red[threadIdx.x] = s;
    __syncthreads();
    for (int o = 128; o >= 1; o >>= 1) {
        if (threadIdx.x < o) red[threadIdx.x] += red[threadIdx.x + o];
        __syncthreads();
    }
    if (threadIdx.x == 0) sigma[0] = (float)(red[0] * (1.0 / 134217728.0));
}

__global__ __launch_bounds__(256) void finalize_kernel(
        const float* __restrict__ mx_buf, const float* __restrict__ mn_buf,
        const float* __restrict__ alpha, const float* __restrict__ beta,
        const float* __restrict__ sigma, float* __restrict__ out) {
#pragma clang fp contract(off)
    const int e = blockIdx.x * 256 + threadIdx.x;
    const int c = e & (CC - 1);
    const float s = sigma[0] + 1e-5f;
    const float a = alpha[c];
    const float bt = beta[c];
    const float off = (a >= 0.f) ? mx_buf[e] : mn_buf[e];
    const float t = off / s;
    out[e] = (t * a) + bt;
}

extern "C" void kernel_launch(void* const* d_in, const int* in_sizes, int n_in,
                              void* d_out, int out_size, void* d_ws, size_t ws_size,
                              hipStream_t stream) {
    (void)in_sizes; (void)n_in; (void)out_size; (void)ws_size;
    const float* xyz   = (const float*)d_in[0];  // [16,3,4096]
    const float* feats = (const float*)d_in[1];  // [16,4096,64]
    const float* alpha = (const float*)d_in[2];  // [64]
    const float* beta  = (const float*)d_in[3];  // [64]
    float* out = (float*)d_out;                  // [16,4096,64]

    char* ws = (char*)d_ws;
    // Lifetimes:
    //   val_buf   [0, 33,554,432)          prep->merge(read); dead after.
    //   mx/mn     alias val region          written by gather (post-merge).
    //   idx_buf   [33,554,432, 41,943,040)  merge/fallback write, gather reads
    //                                       (disjoint from val: merge reads
    //                                       val while writing idx).
    //   flag_list [41,943,040, +256 KB)     merge->fallback.
    //   flag_cnt  42,205,184 (4 B)
    //   pts4      [42,205,200, +1 MB)       prep->select; dead after select.
    //   partials  alias pts4 start          written by gather.
    //   sigma     42,336,272
    // Max used 43,253,776 < 43,319,296 (R12's proven ws extent).
    unsigned* val_buf  = (unsigned*)ws;
    float*    mx_buf   = (float*)ws;                  // [0, 16.78M)
    float*    mn_buf   = (float*)(ws + 16777216);     // [16.78M, 33.55M)
    int*      idx_buf  = (int*)(ws + 33554432);
    int*      flag_list= (int*)(ws + 41943040);
    int*      flag_cnt = (int*)(ws + 42205184);
    float4*   pts4     = (float4*)(ws + 42205200);
    double*   partials = (double*)(ws + 42205200);    // alias pts4 (dead)
    float*    sigma    = (float*)(ws + 42336272);

    prep_kernel<<<NQ / 256, 256, 0, stream>>>(xyz, pts4, flag_cnt);
    knn_select_kernel<<<BB * 16 * NSLICE, 256, 0, stream>>>(pts4, val_buf);
    knn_merge_kernel<<<NQ / 64, 64, 0, stream>>>(val_buf, idx_buf,
                                                 flag_list, flag_cnt);
    knn_fallback_kernel<<<256, 256, 0, stream>>>(xyz, flag_list, flag_cnt,
                                                 idx_buf);
    gather_minmax_kernel<<<NQ / 4, 256, 0, stream>>>(feats, idx_buf, mx_buf,
                                                     mn_buf, partials);
    sigma_kernel<<<1, 256, 0, stream>>>(partials, sigma);
    finalize_kernel<<<(NQ * CC) / 256, 256, 0, stream>>>(mx_buf, mn_buf, alpha,
                                                         beta, sigma, out);
}